// Round 13
// baseline (403.197 us; speedup 1.0000x reference)
//
#include <hip/hip_runtime.h>
#include <hip/hip_fp16.h>
#include <math.h>

#define HID 64
#define HEADS 4
#define HC 256             // HEADS*HID
#define IN_DIM 32
#define NEG 0.2f
#define BN_EPS 1e-5f
#define CAP 64             // max stored in-degree (Poisson(16); P(>=64)~1e-20)

typedef _Float16 f16;
typedef _Float16 f16x8 __attribute__((ext_vector_type(8)));
typedef float f32x4 __attribute__((ext_vector_type(4)));

// ---------- helpers ----------
__device__ __forceinline__ int ld_idx(const int* __restrict__ p, int i, int f64) {
    return f64 ? p[(size_t)2 * i] : p[i];
}

// init (zero deg/gsum, detect int64) + prep (wtilde + BT); blocks 0..2 do prep
__global__ void k_init(const int* __restrict__ ei, int* __restrict__ flag,
                       int* __restrict__ deg, float* __restrict__ gsum,
                       int N, int NG,
                       const float* __restrict__ gat_W, const float* __restrict__ asrc,
                       const float* __restrict__ adst, float* __restrict__ wts,
                       float* __restrict__ wtd, __half* __restrict__ BT) {
    int i = blockIdx.x * blockDim.x + threadIdx.x;
    if (i == 0) {
        int z = 1;
#pragma unroll
        for (int k = 1; k < 64; k += 2) z &= (ei[k] == 0);
        *flag = z;
    }
    if (i < N) deg[i] = 0;
    if (i < NG) gsum[i] = 0.f;
    if (blockIdx.x < 3) {   // prep for layer l = blockIdx.x
        int l = blockIdx.x;
        int t = threadIdx.x;           // 0..255
        int hh = t >> 6, k = t & 63;
        {   // wtilde
            const float* W = gat_W + (size_t)l * HID * HC + (size_t)k * HC + hh * HID;
            const float* as = asrc + (size_t)l * HEADS * HID + hh * HID;
            const float* ad = adst + (size_t)l * HEADS * HID + hh * HID;
            float s1 = 0.f, s2 = 0.f;
#pragma unroll
            for (int c = 0; c < HID; ++c) { s1 += W[c] * as[c]; s2 += W[c] * ad[c]; }
            wts[l * HC + hh * HID + k] = s1;
            wtd[l * HC + hh * HID + k] = s2;
        }
        {   // BT[l][c][j] = W[l][j&63][(j>>6)*64 + c] fp16
            int c = t & 63, jg = t >> 6;
            const float* W = gat_W + (size_t)l * HID * HC;
            __half* o = BT + (size_t)l * HID * HC + (size_t)c * HC + jg * 64;
#pragma unroll
            for (int jj = 0; jj < 64; ++jj)
                o[jj] = __float2half(W[(size_t)jj * HC + jg * 64 + c]);
        }
    }
}

// ---------- fused: CSR build (blocks < nb_build) + input GEMM (rest) ----------
// build: memory-scatter-bound, VALU ~1%; input hides under it.
__global__ __launch_bounds__(256) void k_build_input(
        const int* __restrict__ ei, const int* __restrict__ flagp,
        int* __restrict__ deg, unsigned short* __restrict__ src_pad, int E,
        const float* __restrict__ x, const float* __restrict__ W,
        const float* __restrict__ b, const float* __restrict__ wts0,
        const float* __restrict__ wtd0, float* __restrict__ h,
        __half* __restrict__ h16, float* __restrict__ ssrc,
        float* __restrict__ sdst, int N, int nb_build) {
    const int f = *flagp;
    if ((int)blockIdx.x < nb_build) {
        int e = blockIdx.x * 256 + threadIdx.x;
        if (e >= E) return;
        int s = ld_idx(ei, e, f);
        int d = ld_idx(ei, E + e, f);
        int pos = atomicAdd(&deg[d], 1);
        if (pos < CAP) src_pad[(size_t)d * CAP + pos] = (unsigned short)s;
        return;
    }
    int blk = blockIdx.x - nb_build;
    int w = threadIdx.x >> 6, lane = threadIdx.x & 63;
    int n = blk * 4 + w;
    if (n >= N) return;
    float xv = x[(size_t)n * IN_DIM + (lane & 31)];
    float acc = b[lane];
#pragma unroll
    for (int k = 0; k < IN_DIM; ++k)
        acc += __shfl(xv, k, 64) * W[k * HID + lane];
    h[(size_t)n * HID + lane] = acc;
    h16[(size_t)n * HID + lane] = __float2half(acc);
    float p0 = acc * wts0[0 * HID + lane];
    float p1 = acc * wts0[1 * HID + lane];
    float p2 = acc * wts0[2 * HID + lane];
    float p3 = acc * wts0[3 * HID + lane];
    float q0 = acc * wtd0[0 * HID + lane];
    float q1 = acc * wtd0[1 * HID + lane];
    float q2 = acc * wtd0[2 * HID + lane];
    float q3 = acc * wtd0[3 * HID + lane];
#pragma unroll
    for (int m = 32; m >= 1; m >>= 1) {
        p0 += __shfl_xor(p0, m, 64); p1 += __shfl_xor(p1, m, 64);
        p2 += __shfl_xor(p2, m, 64); p3 += __shfl_xor(p3, m, 64);
        q0 += __shfl_xor(q0, m, 64); q1 += __shfl_xor(q1, m, 64);
        q2 += __shfl_xor(q2, m, 64); q3 += __shfl_xor(q3, m, 64);
    }
    if (lane == 0) {
        *(float4*)(ssrc + (size_t)n * HEADS) = make_float4(p0, p1, p2, p3);
        *(float4*)(sdst + (size_t)n * HEADS) = make_float4(q0, q1, q2, q3);
    }
}

// ---------- gather v3: wave per dst node, 8 edges/iteration (8 lanes/edge) ----------
// Edge stream: slot 0 = self-loop, slots 1..dg = src_pad. Lane: g=lane>>3 edge
// slot in octet, l8=lane&7 channel octet (16B h16 load). 2-deep pipeline; per
// load-inst 8 cache-line transactions -> 4x the in-flight requests of v2.
__global__ __launch_bounds__(256) void k_gather(
        const int* __restrict__ deg, const unsigned short* __restrict__ src_pad,
        const float* __restrict__ ssrc, const float* __restrict__ sdst,
        const __half* __restrict__ h16, __half* __restrict__ agg, int N) {
    int d = blockIdx.x * 4 + (threadIdx.x >> 6);
    if (d >= N) return;
    const int lane = threadIdx.x & 63;
    const int g = lane >> 3, l8 = lane & 7;
    const int dg = min(deg[d], CAP);
    const int tot = dg + 1;         // + self at slot 0
    const int se = (int)src_pad[(size_t)d * CAP + lane];
    const float4 sdd = *(const float4*)(sdst + (size_t)d * HEADS);
    float den0 = 0.f, den1 = 0.f, den2 = 0.f, den3 = 0.f;
    float acc0[8], acc1[8], acc2[8], acc3[8];
#pragma unroll
    for (int i = 0; i < 8; ++i) { acc0[i] = 0.f; acc1[i] = 0.f; acc2[i] = 0.f; acc3[i] = 0.f; }

    // prologue: slot idx0 = g
    bool vc = g < tot;
    int sc;
    {
        int sj = __shfl(se, (g - 1) & 63, 64);
        sc = (g == 0) ? d : sj;
        sc = vc ? sc : d;
    }
    float4 ss_cur = *(const float4*)(ssrc + (size_t)sc * HEADS);
    uint4  hu_cur = *(const uint4*)(h16 + (size_t)sc * HID + l8 * 8);

    for (int b = 0; b < tot; b += 8) {
        // issue next octet's loads
        int idn = b + 8 + g;
        bool vn = idn < tot;
        int sn;
        {
            int sj = __shfl(se, (idn - 1) & 63, 64);
            sn = vn ? sj : d;           // idn >= 8, never the self slot
        }
        float4 ss_nxt = *(const float4*)(ssrc + (size_t)sn * HEADS);
        uint4  hu_nxt = *(const uint4*)(h16 + (size_t)sn * HID + l8 * 8);
        // compute current octet
        float u0 = ss_cur.x + sdd.x; u0 = u0 > 0.f ? u0 : NEG * u0;
        float u1 = ss_cur.y + sdd.y; u1 = u1 > 0.f ? u1 : NEG * u1;
        float u2 = ss_cur.z + sdd.z; u2 = u2 > 0.f ? u2 : NEG * u2;
        float u3 = ss_cur.w + sdd.w; u3 = u3 > 0.f ? u3 : NEG * u3;
        float e0 = vc ? __expf(u0) : 0.f;
        float e1 = vc ? __expf(u1) : 0.f;
        float e2 = vc ? __expf(u2) : 0.f;
        float e3 = vc ? __expf(u3) : 0.f;
        const __half2* hp = (const __half2*)&hu_cur;
        float2 f0 = __half22float2(hp[0]);
        float2 f1 = __half22float2(hp[1]);
        float2 f2 = __half22float2(hp[2]);
        float2 f3 = __half22float2(hp[3]);
        float fv[8] = {f0.x, f0.y, f1.x, f1.y, f2.x, f2.y, f3.x, f3.y};
        den0 += e0; den1 += e1; den2 += e2; den3 += e3;
#pragma unroll
        for (int i = 0; i < 8; ++i) {
            acc0[i] += e0 * fv[i];
            acc1[i] += e1 * fv[i];
            acc2[i] += e2 * fv[i];
            acc3[i] += e3 * fv[i];
        }
        ss_cur = ss_nxt; hu_cur = hu_nxt; vc = vn;
    }
#define FOLD(v) { v += __shfl_xor(v, 8, 64); v += __shfl_xor(v, 16, 64); v += __shfl_xor(v, 32, 64); }
    FOLD(den0) FOLD(den1) FOLD(den2) FOLD(den3)
#pragma unroll
    for (int i = 0; i < 8; ++i) {
        FOLD(acc0[i]) FOLD(acc1[i]) FOLD(acc2[i]) FOLD(acc3[i])
    }
#undef FOLD
    if (lane < 32) {                 // lane = hh*8 + l8 writes head hh, octet l8
        int hh = lane >> 3;
        float dh = hh == 0 ? den0 : hh == 1 ? den1 : hh == 2 ? den2 : den3;
        float iv = 0.25f / dh;
        float o[8];
#pragma unroll
        for (int i = 0; i < 8; ++i) {
            float a = hh == 0 ? acc0[i] : hh == 1 ? acc1[i] : hh == 2 ? acc2[i] : acc3[i];
            o[i] = a * iv;
        }
        __half2 hp0 = __floats2half2_rn(o[0], o[1]);
        __half2 hp1 = __floats2half2_rn(o[2], o[3]);
        __half2 hp2 = __floats2half2_rn(o[4], o[5]);
        __half2 hp3 = __floats2half2_rn(o[6], o[7]);
        uint4 st;
        st.x = *(unsigned*)&hp0; st.y = *(unsigned*)&hp1;
        st.z = *(unsigned*)&hp2; st.w = *(unsigned*)&hp3;
        *(uint4*)(agg + ((size_t)d * HC + hh * HID + l8 * 8)) = st;
    }
}

// ---------- postW via MFMA: out[n][c] = sum_j agg[n][j]*BT[c][j] ----------
__global__ __launch_bounds__(256) void k_postW(
        const __half* __restrict__ agg, const __half* __restrict__ BT,
        const float* __restrict__ gb, const float* __restrict__ bg,
        const float* __restrict__ bb, const float* __restrict__ bm,
        const float* __restrict__ bv, const float* __restrict__ wtsn,
        const float* __restrict__ wtdn, float* __restrict__ h,
        __half* __restrict__ h16, float* __restrict__ ssrc,
        float* __restrict__ sdst, int N) {
    __shared__ float lds[64][68];   // pad 68: conflict-free + 16B aligned
    const int t = threadIdx.x;
    const int w = t >> 6, l = t & 63;
    const int l16 = l & 15, lk = l >> 4;
    const f16* BTf = (const f16*)BT;
    const f16* af = (const f16*)agg;
    int row = blockIdx.x * 64 + w * 16 + l16;
    int rowc = min(row, N - 1);
    f32x4 acc[4];
#pragma unroll
    for (int nt = 0; nt < 4; ++nt) acc[nt] = (f32x4){0.f, 0.f, 0.f, 0.f};
#pragma unroll
    for (int ks = 0; ks < 8; ++ks) {
        f16x8 a = *(const f16x8*)(af + (size_t)rowc * HC + ks * 32 + lk * 8);
#pragma unroll
        for (int nt = 0; nt < 4; ++nt) {
            f16x8 bfr = *(const f16x8*)(BTf + (size_t)(nt * 16 + l16) * HC + ks * 32 + lk * 8);
            acc[nt] = __builtin_amdgcn_mfma_f32_16x16x32_f16(a, bfr, acc[nt], 0, 0, 0);
        }
    }
#pragma unroll
    for (int nt = 0; nt < 4; ++nt)
#pragma unroll
        for (int r = 0; r < 4; ++r)
            lds[w * 16 + lk * 4 + r][nt * 16 + l16] = acc[nt][r];
    __syncthreads();
    {   // epilogue: thread t owns node j=t>>2, cols q*16..+15 (q=t&3)
        int j = t >> 2, q = t & 3;
        int n = blockIdx.x * 64 + j;
        if (n < N) {
            int c0 = q * 16;
            float o[16];
            float* hrow = h + (size_t)n * HID;
#pragma unroll
            for (int i4 = 0; i4 < 4; ++i4) {
                int c = c0 + i4 * 4;
                float4 sv = *(const float4*)&lds[j][c];
                float4 r4 = *(const float4*)(hrow + c);
                float4 gb4 = *(const float4*)(gb + c);
                float4 bg4 = *(const float4*)(bg + c);
                float4 bb4 = *(const float4*)(bb + c);
                float4 bm4 = *(const float4*)(bm + c);
                float4 bv4 = *(const float4*)(bv + c);
                float4 ov;
                float v;
                v = sv.x + gb4.x; v = (v - bm4.x) * rsqrtf(bv4.x + BN_EPS) * bg4.x + bb4.x;
                ov.x = fmaxf(v, 0.f) + r4.x;
                v = sv.y + gb4.y; v = (v - bm4.y) * rsqrtf(bv4.y + BN_EPS) * bg4.y + bb4.y;
                ov.y = fmaxf(v, 0.f) + r4.y;
                v = sv.z + gb4.z; v = (v - bm4.z) * rsqrtf(bv4.z + BN_EPS) * bg4.z + bb4.z;
                ov.z = fmaxf(v, 0.f) + r4.z;
                v = sv.w + gb4.w; v = (v - bm4.w) * rsqrtf(bv4.w + BN_EPS) * bg4.w + bb4.w;
                ov.w = fmaxf(v, 0.f) + r4.w;
                *(float4*)(hrow + c) = ov;
                o[i4 * 4 + 0] = ov.x; o[i4 * 4 + 1] = ov.y;
                o[i4 * 4 + 2] = ov.z; o[i4 * 4 + 3] = ov.w;
            }
            {
                __half2 hp[8];
#pragma unroll
                for (int i = 0; i < 8; ++i)
                    hp[i] = __floats2half2_rn(o[2 * i], o[2 * i + 1]);
                uint4 u0, u1;
                u0.x = *(unsigned*)&hp[0]; u0.y = *(unsigned*)&hp[1];
                u0.z = *(unsigned*)&hp[2]; u0.w = *(unsigned*)&hp[3];
                u1.x = *(unsigned*)&hp[4]; u1.y = *(unsigned*)&hp[5];
                u1.z = *(unsigned*)&hp[6]; u1.w = *(unsigned*)&hp[7];
                *(uint4*)(h16 + (size_t)n * HID + c0) = u0;
                *(uint4*)(h16 + (size_t)n * HID + c0 + 8) = u1;
            }
            if (wtsn) {
                float ps0 = 0.f, ps1 = 0.f, ps2 = 0.f, ps3 = 0.f;
                float pd0 = 0.f, pd1 = 0.f, pd2 = 0.f, pd3 = 0.f;
#pragma unroll
                for (int i = 0; i < 16; ++i) {
                    int c = c0 + i;
                    float ov = o[i];
                    ps0 += ov * wtsn[0 * HID + c]; ps1 += ov * wtsn[1 * HID + c];
                    ps2 += ov * wtsn[2 * HID + c]; ps3 += ov * wtsn[3 * HID + c];
                    pd0 += ov * wtdn[0 * HID + c]; pd1 += ov * wtdn[1 * HID + c];
                    pd2 += ov * wtdn[2 * HID + c]; pd3 += ov * wtdn[3 * HID + c];
                }
#pragma unroll
                for (int m = 2; m >= 1; m >>= 1) {
                    ps0 += __shfl_xor(ps0, m, 64); ps1 += __shfl_xor(ps1, m, 64);
                    ps2 += __shfl_xor(ps2, m, 64); ps3 += __shfl_xor(ps3, m, 64);
                    pd0 += __shfl_xor(pd0, m, 64); pd1 += __shfl_xor(pd1, m, 64);
                    pd2 += __shfl_xor(pd2, m, 64); pd3 += __shfl_xor(pd3, m, 64);
                }
                if (q == 0) {
                    *(float4*)(ssrc + (size_t)n * HEADS) = make_float4(ps0, ps1, ps2, ps3);
                    *(float4*)(sdst + (size_t)n * HEADS) = make_float4(pd0, pd1, pd2, pd3);
                }
            }
        }
    }
}

// ---------- global mean pool: node-parallel partial sums ----------
#define NPBK 64
__global__ void k_pool_sum(const float* __restrict__ h, const int* __restrict__ batch,
                           const int* __restrict__ flagp, float* __restrict__ gsum, int N) {
    const int f = *flagp;
    int c = threadIdx.x;  // 0..63
    int n0 = blockIdx.x * NPBK;
    int n1 = min(n0 + NPBK, N);
    if (n0 >= N) return;
    int cur = ld_idx(batch, n0, f);
    float s = 0.f;
    for (int n = n0; n < n1; ++n) {
        int g = ld_idx(batch, n, f);
        if (g != cur) {
            atomicAdd(&gsum[cur * HID + c], s);
            s = 0.f;
            cur = g;
        }
        s += h[(size_t)n * HID + c];
    }
    atomicAdd(&gsum[cur * HID + c], s);
}

__device__ __forceinline__ int lower_bound_i(const int* __restrict__ a, int n, int v, int f) {
    int lo = 0, hi = n;
    while (lo < hi) {
        int mid = (lo + hi) >> 1;
        if (ld_idx(a, mid, f) < v) lo = mid + 1; else hi = mid;
    }
    return lo;
}

// ---------- final MLP head ----------
__global__ void k_mlp(const float* __restrict__ gsum, const int* __restrict__ batch,
                      const int* __restrict__ flagp, int N,
                      const float* __restrict__ W1, const float* __restrict__ b1,
                      const float* __restrict__ W2, const float* __restrict__ b2,
                      float* __restrict__ out, int OUTD) {
    int gg = blockIdx.x, c = threadIdx.x;  // 64 threads
    const int f = *flagp;
    int lo = lower_bound_i(batch, N, gg, f);
    int hi = lower_bound_i(batch, N, gg + 1, f);
    float cnt = (float)(hi - lo);
    __shared__ float gs[HID];
    __shared__ float s1[HID];
    gs[c] = gsum[gg * HID + c] / fmaxf(cnt, 1.f);
    __syncthreads();
    float acc = b1[c];
#pragma unroll
    for (int k = 0; k < HID; ++k) acc += gs[k] * W1[k * HID + c];
    s1[c] = fmaxf(acc, 0.f);
    __syncthreads();
    if (c < OUTD) {
        float o = b2[c];
#pragma unroll
        for (int k = 0; k < HID; ++k) o += s1[k] * W2[k * OUTD + c];
        out[gg * OUTD + c] = o;
    }
}

extern "C" void kernel_launch(void* const* d_in, const int* in_sizes, int n_in,
                              void* d_out, int out_size, void* d_ws, size_t ws_size,
                              hipStream_t stream) {
    const float* x       = (const float*)d_in[0];
    const int*   ei_raw  = (const int*)d_in[1];
    const int*   b_raw   = (const int*)d_in[2];
    const float* in_W    = (const float*)d_in[3];
    const float* in_b    = (const float*)d_in[4];
    const float* gat_W   = (const float*)d_in[5];
    const float* att_src = (const float*)d_in[6];
    const float* att_dst = (const float*)d_in[7];
    const float* gat_b   = (const float*)d_in[8];
    const float* bn_g    = (const float*)d_in[9];
    const float* bn_b    = (const float*)d_in[10];
    const float* bn_m    = (const float*)d_in[11];
    const float* bn_v    = (const float*)d_in[12];
    const float* fc1_W   = (const float*)d_in[13];
    const float* fc1_b   = (const float*)d_in[14];
    const float* fc2_W   = (const float*)d_in[15];
    const float* fc2_b   = (const float*)d_in[16];

    const int N = in_sizes[2];          // n_nodes (<= 65536 for ushort path)
    const int E = in_sizes[1] / 2;      // edges
    const int OUTD = 4;
    const int G = out_size / OUTD;
    const int nb_build = (E + 255) / 256;
    const int nb_input = (N + 3) / 4;

    // ---- workspace layout (~53.0 MB) ----
    float*  h    = (float*)d_ws;                         // N*64 fp32      12.8 MB
    __half* h16  = (__half*)(h + (size_t)N * HID);       // N*64 fp16       6.4 MB
    __half* agg  = h16 + (size_t)N * HID;                // N*256 fp16     25.6 MB
    float*  ssrc = (float*)(agg + (size_t)N * HC);       // N*4
    float*  sdst = ssrc + (size_t)N * HEADS;             // N*4
    float*  wts  = sdst + (size_t)N * HEADS;             // 3*256
    float*  wtd  = wts + 3 * HC;                         // 3*256
    __half* BT   = (__half*)(wtd + 3 * HC);              // 3*64*256 fp16  96 KB
    float*  gsum = (float*)(BT + 3 * HID * HC);          // G*64
    int*    deg  = (int*)(gsum + (size_t)G * HID);       // N
    unsigned short* src_pad = (unsigned short*)(deg + N);// N*CAP ushort    6.4 MB
    int*    flag = (int*)(src_pad + (size_t)N * CAP);    // 1

    k_init<<<(max(N, G * HID) + 255) / 256, 256, 0, stream>>>(
        ei_raw, flag, deg, gsum, N, G * HID,
        gat_W, att_src, att_dst, wts, wtd, BT);
    k_build_input<<<nb_build + nb_input, 256, 0, stream>>>(
        ei_raw, flag, deg, src_pad, E,
        x, in_W, in_b, wts, wtd, h, h16, ssrc, sdst, N, nb_build);

    for (int l = 0; l < 3; ++l) {
        k_gather<<<(N + 3) / 4, 256, 0, stream>>>(
            deg, src_pad, ssrc, sdst, h16, agg, N);
        const float* wtsn = (l < 2) ? (wts + (l + 1) * HC) : nullptr;
        const float* wtdn = (l < 2) ? (wtd + (l + 1) * HC) : nullptr;
        k_postW<<<(N + 63) / 64, 256, 0, stream>>>(
            agg, BT + (size_t)l * HID * HC,
            gat_b + (size_t)l * HID, bn_g + (size_t)l * HID, bn_b + (size_t)l * HID,
            bn_m + (size_t)l * HID, bn_v + (size_t)l * HID,
            wtsn, wtdn, h, h16, ssrc, sdst, N);
    }

    k_pool_sum<<<(N + NPBK - 1) / NPBK, HID, 0, stream>>>(h, b_raw, flag, gsum, N);
    k_mlp<<<G, HID, 0, stream>>>(gsum, b_raw, flag, N, fc1_W, fc1_b, fc2_W, fc2_b,
                                 (float*)d_out, OUTD);
}

// Round 14
// 327.977 us; speedup vs baseline: 1.2293x; 1.2293x over previous
//
#include <hip/hip_runtime.h>
#include <hip/hip_fp16.h>
#include <math.h>

#define HID 64
#define HEADS 4
#define HC 256             // HEADS*HID
#define IN_DIM 32
#define NEG 0.2f
#define BN_EPS 1e-5f
#define CAP 64             // max stored in-degree (Poisson(16); P(>=64)~1e-20)

typedef _Float16 f16;
typedef _Float16 f16x8 __attribute__((ext_vector_type(8)));
typedef float f32x4 __attribute__((ext_vector_type(4)));

// ---------- helpers ----------
__device__ __forceinline__ int ld_idx(const int* __restrict__ p, int i, int f64) {
    return f64 ? p[(size_t)2 * i] : p[i];
}

// init (zero deg/gsum, detect int64) + prep (wtilde + BT); blocks 0..2 do prep
__global__ void k_init(const int* __restrict__ ei, int* __restrict__ flag,
                       int* __restrict__ deg, float* __restrict__ gsum,
                       int N, int NG,
                       const float* __restrict__ gat_W, const float* __restrict__ asrc,
                       const float* __restrict__ adst, float* __restrict__ wts,
                       float* __restrict__ wtd, __half* __restrict__ BT) {
    int i = blockIdx.x * blockDim.x + threadIdx.x;
    if (i == 0) {
        int z = 1;
#pragma unroll
        for (int k = 1; k < 64; k += 2) z &= (ei[k] == 0);
        *flag = z;
    }
    if (i < N) deg[i] = 0;
    if (i < NG) gsum[i] = 0.f;
    if (blockIdx.x < 3) {   // prep for layer l = blockIdx.x
        int l = blockIdx.x;
        int t = threadIdx.x;           // 0..255
        int hh = t >> 6, k = t & 63;
        {   // wtilde
            const float* W = gat_W + (size_t)l * HID * HC + (size_t)k * HC + hh * HID;
            const float* as = asrc + (size_t)l * HEADS * HID + hh * HID;
            const float* ad = adst + (size_t)l * HEADS * HID + hh * HID;
            float s1 = 0.f, s2 = 0.f;
#pragma unroll
            for (int c = 0; c < HID; ++c) { s1 += W[c] * as[c]; s2 += W[c] * ad[c]; }
            wts[l * HC + hh * HID + k] = s1;
            wtd[l * HC + hh * HID + k] = s2;
        }
        {   // BT[l][c][j] = W[l][j&63][(j>>6)*64 + c] fp16
            int c = t & 63, jg = t >> 6;
            const float* W = gat_W + (size_t)l * HID * HC;
            __half* o = BT + (size_t)l * HID * HC + (size_t)c * HC + jg * 64;
#pragma unroll
            for (int jj = 0; jj < 64; ++jj)
                o[jj] = __float2half(W[(size_t)jj * HC + jg * 64 + c]);
        }
    }
}

// ---------- single-pass padded-bucket CSR (atomics spread over N addresses) ----------
__global__ void k_build(const int* __restrict__ ei, const int* __restrict__ flagp,
                        int* __restrict__ deg, unsigned short* __restrict__ src_pad,
                        int E) {
    int e = blockIdx.x * blockDim.x + threadIdx.x;
    if (e >= E) return;
    const int f = *flagp;
    int s = ld_idx(ei, e, f);
    int d = ld_idx(ei, E + e, f);
    int pos = atomicAdd(&deg[d], 1);
    if (pos < CAP) src_pad[(size_t)d * CAP + pos] = (unsigned short)s;
}

// ---------- h = x @ in_W + in_b (fp32 + fp16) + layer-0 scores ----------
__global__ __launch_bounds__(256) void k_input(
        const float* __restrict__ x, const float* __restrict__ W,
        const float* __restrict__ b, const float* __restrict__ wts0,
        const float* __restrict__ wtd0, float* __restrict__ h,
        __half* __restrict__ h16, float* __restrict__ ssrc,
        float* __restrict__ sdst, int N) {
    int w = threadIdx.x >> 6, lane = threadIdx.x & 63;
    int n = blockIdx.x * 4 + w;
    if (n >= N) return;
    float xv = x[(size_t)n * IN_DIM + (lane & 31)];
    float acc = b[lane];
#pragma unroll
    for (int k = 0; k < IN_DIM; ++k)
        acc += __shfl(xv, k, 64) * W[k * HID + lane];
    h[(size_t)n * HID + lane] = acc;
    h16[(size_t)n * HID + lane] = __float2half(acc);
    float p0 = acc * wts0[0 * HID + lane];
    float p1 = acc * wts0[1 * HID + lane];
    float p2 = acc * wts0[2 * HID + lane];
    float p3 = acc * wts0[3 * HID + lane];
    float q0 = acc * wtd0[0 * HID + lane];
    float q1 = acc * wtd0[1 * HID + lane];
    float q2 = acc * wtd0[2 * HID + lane];
    float q3 = acc * wtd0[3 * HID + lane];
#pragma unroll
    for (int m = 32; m >= 1; m >>= 1) {
        p0 += __shfl_xor(p0, m, 64); p1 += __shfl_xor(p1, m, 64);
        p2 += __shfl_xor(p2, m, 64); p3 += __shfl_xor(p3, m, 64);
        q0 += __shfl_xor(q0, m, 64); q1 += __shfl_xor(q1, m, 64);
        q2 += __shfl_xor(q2, m, 64); q3 += __shfl_xor(q3, m, 64);
    }
    if (lane == 0) {
        *(float4*)(ssrc + (size_t)n * HEADS) = make_float4(p0, p1, p2, p3);
        *(float4*)(sdst + (size_t)n * HEADS) = make_float4(q0, q1, q2, q3);
    }
}

// ---------- gather: wave per dst node, 4 edges/iteration, 2-deep pipeline ----------
__global__ __launch_bounds__(256) void k_gather(
        const int* __restrict__ deg, const unsigned short* __restrict__ src_pad,
        const float* __restrict__ ssrc, const float* __restrict__ sdst,
        const __half* __restrict__ h16, __half* __restrict__ agg, int N) {
    int d = blockIdx.x * 4 + (threadIdx.x >> 6);
    if (d >= N) return;
    const int lane = threadIdx.x & 63;
    const int g = lane >> 4, l16 = lane & 15;
    const int dg = min(deg[d], CAP);
    const int se = (int)src_pad[(size_t)d * CAP + lane];
    const float4 sdd = *(const float4*)(sdst + (size_t)d * HEADS);
    float den0 = 0.f, den1 = 0.f, den2 = 0.f, den3 = 0.f;
    float a00=0.f,a01=0.f,a02=0.f,a03=0.f, a10=0.f,a11=0.f,a12=0.f,a13=0.f;
    float a20=0.f,a21=0.f,a22=0.f,a23=0.f, a30=0.f,a31=0.f,a32=0.f,a33=0.f;
    {   // self-loop: group 0 only
        float4 ssd = *(const float4*)(ssrc + (size_t)d * HEADS);
        uint2 hu = *(const uint2*)(h16 + (size_t)d * HID + l16 * 4);
        float2 f01 = __half22float2(*(__half2*)&hu.x);
        float2 f23 = __half22float2(*(__half2*)&hu.y);
        if (g == 0) {
            float v0 = ssd.x + sdd.x; v0 = v0 > 0.f ? v0 : NEG * v0;
            float v1 = ssd.y + sdd.y; v1 = v1 > 0.f ? v1 : NEG * v1;
            float v2 = ssd.z + sdd.z; v2 = v2 > 0.f ? v2 : NEG * v2;
            float v3 = ssd.w + sdd.w; v3 = v3 > 0.f ? v3 : NEG * v3;
            float e0 = __expf(v0), e1 = __expf(v1), e2 = __expf(v2), e3 = __expf(v3);
            den0 = e0; den1 = e1; den2 = e2; den3 = e3;
            a00 = e0*f01.x; a01 = e0*f01.y; a02 = e0*f23.x; a03 = e0*f23.y;
            a10 = e1*f01.x; a11 = e1*f01.y; a12 = e1*f23.x; a13 = e1*f23.y;
            a20 = e2*f01.x; a21 = e2*f01.y; a22 = e2*f23.x; a23 = e2*f23.y;
            a30 = e3*f01.x; a31 = e3*f01.y; a32 = e3*f23.x; a33 = e3*f23.y;
        }
    }
    // pipelined edge loop: issue iter i+1's loads before computing iter i
    bool vc = g < dg;
    int sc = __shfl(se, g, 64); sc = vc ? sc : d;
    float4 ss_cur = *(const float4*)(ssrc + (size_t)sc * HEADS);
    uint2  hu_cur = *(const uint2*)(h16 + (size_t)sc * HID + l16 * 4);
    for (int b = 0; b < dg; b += 4) {
        int idn = b + 4 + g;
        bool vn = idn < dg;
        int sn = __shfl(se, idn & 63, 64); sn = vn ? sn : d;
        float4 ss_nxt = *(const float4*)(ssrc + (size_t)sn * HEADS);
        uint2  hu_nxt = *(const uint2*)(h16 + (size_t)sn * HID + l16 * 4);
        float u0 = ss_cur.x + sdd.x; u0 = u0 > 0.f ? u0 : NEG * u0;
        float u1 = ss_cur.y + sdd.y; u1 = u1 > 0.f ? u1 : NEG * u1;
        float u2 = ss_cur.z + sdd.z; u2 = u2 > 0.f ? u2 : NEG * u2;
        float u3 = ss_cur.w + sdd.w; u3 = u3 > 0.f ? u3 : NEG * u3;
        float e0 = vc ? __expf(u0) : 0.f;
        float e1 = vc ? __expf(u1) : 0.f;
        float e2 = vc ? __expf(u2) : 0.f;
        float e3 = vc ? __expf(u3) : 0.f;
        float2 f01 = __half22float2(*(__half2*)&hu_cur.x);
        float2 f23 = __half22float2(*(__half2*)&hu_cur.y);
        den0 += e0; den1 += e1; den2 += e2; den3 += e3;
        a00 += e0*f01.x; a01 += e0*f01.y; a02 += e0*f23.x; a03 += e0*f23.y;
        a10 += e1*f01.x; a11 += e1*f01.y; a12 += e1*f23.x; a13 += e1*f23.y;
        a20 += e2*f01.x; a21 += e2*f01.y; a22 += e2*f23.x; a23 += e2*f23.y;
        a30 += e3*f01.x; a31 += e3*f01.y; a32 += e3*f23.x; a33 += e3*f23.y;
        ss_cur = ss_nxt; hu_cur = hu_nxt; vc = vn;
    }
#define FOLD(v) { v += __shfl_xor(v, 16, 64); v += __shfl_xor(v, 32, 64); }
    FOLD(den0) FOLD(den1) FOLD(den2) FOLD(den3)
    FOLD(a00) FOLD(a01) FOLD(a02) FOLD(a03)
    FOLD(a10) FOLD(a11) FOLD(a12) FOLD(a13)
    FOLD(a20) FOLD(a21) FOLD(a22) FOLD(a23)
    FOLD(a30) FOLD(a31) FOLD(a32) FOLD(a33)
#undef FOLD
    float iv, o0, o1, o2, o3;
    if (g == 0)      { iv = 0.25f / den0; o0 = a00; o1 = a01; o2 = a02; o3 = a03; }
    else if (g == 1) { iv = 0.25f / den1; o0 = a10; o1 = a11; o2 = a12; o3 = a13; }
    else if (g == 2) { iv = 0.25f / den2; o0 = a20; o1 = a21; o2 = a22; o3 = a23; }
    else             { iv = 0.25f / den3; o0 = a30; o1 = a31; o2 = a32; o3 = a33; }
    __half2 q01 = __floats2half2_rn(o0 * iv, o1 * iv);
    __half2 q23 = __floats2half2_rn(o2 * iv, o3 * iv);
    uint2 st;
    st.x = *(unsigned int*)&q01;
    st.y = *(unsigned int*)&q23;
    *(uint2*)(agg + ((size_t)d * HC + g * HID + l16 * 4)) = st;
}

// ---------- postW via MFMA: out[n][c] = sum_j agg[n][j]*BT[c][j] ----------
// B-frags loaded in-loop (L2-hot 32KB) -> low VGPR -> higher occupancy.
__global__ __launch_bounds__(256) void k_postW(
        const __half* __restrict__ agg, const __half* __restrict__ BT,
        const float* __restrict__ gb, const float* __restrict__ bg,
        const float* __restrict__ bb, const float* __restrict__ bm,
        const float* __restrict__ bv, const float* __restrict__ wtsn,
        const float* __restrict__ wtdn, float* __restrict__ h,
        __half* __restrict__ h16, float* __restrict__ ssrc,
        float* __restrict__ sdst, int N) {
    __shared__ float lds[64][68];   // pad 68: conflict-free + 16B aligned
    const int t = threadIdx.x;
    const int w = t >> 6, l = t & 63;
    const int l16 = l & 15, lk = l >> 4;
    const f16* BTf = (const f16*)BT;
    const f16* af = (const f16*)agg;
    int row = blockIdx.x * 64 + w * 16 + l16;
    int rowc = min(row, N - 1);
    f32x4 acc[4];
#pragma unroll
    for (int nt = 0; nt < 4; ++nt) acc[nt] = (f32x4){0.f, 0.f, 0.f, 0.f};
#pragma unroll
    for (int ks = 0; ks < 8; ++ks) {
        f16x8 a = *(const f16x8*)(af + (size_t)rowc * HC + ks * 32 + lk * 8);
#pragma unroll
        for (int nt = 0; nt < 4; ++nt) {
            f16x8 bfr = *(const f16x8*)(BTf + (size_t)(nt * 16 + l16) * HC + ks * 32 + lk * 8);
            acc[nt] = __builtin_amdgcn_mfma_f32_16x16x32_f16(a, bfr, acc[nt], 0, 0, 0);
        }
    }
#pragma unroll
    for (int nt = 0; nt < 4; ++nt)
#pragma unroll
        for (int r = 0; r < 4; ++r)
            lds[w * 16 + lk * 4 + r][nt * 16 + l16] = acc[nt][r];
    __syncthreads();
    {   // epilogue: thread t owns node j=t>>2, cols q*16..+15 (q=t&3)
        int j = t >> 2, q = t & 3;
        int n = blockIdx.x * 64 + j;
        if (n < N) {
            int c0 = q * 16;
            float o[16];
            float* hrow = h + (size_t)n * HID;
#pragma unroll
            for (int i4 = 0; i4 < 4; ++i4) {
                int c = c0 + i4 * 4;
                float4 sv = *(const float4*)&lds[j][c];
                float4 r4 = *(const float4*)(hrow + c);
                float4 gb4 = *(const float4*)(gb + c);
                float4 bg4 = *(const float4*)(bg + c);
                float4 bb4 = *(const float4*)(bb + c);
                float4 bm4 = *(const float4*)(bm + c);
                float4 bv4 = *(const float4*)(bv + c);
                float4 ov;
                float v;
                v = sv.x + gb4.x; v = (v - bm4.x) * rsqrtf(bv4.x + BN_EPS) * bg4.x + bb4.x;
                ov.x = fmaxf(v, 0.f) + r4.x;
                v = sv.y + gb4.y; v = (v - bm4.y) * rsqrtf(bv4.y + BN_EPS) * bg4.y + bb4.y;
                ov.y = fmaxf(v, 0.f) + r4.y;
                v = sv.z + gb4.z; v = (v - bm4.z) * rsqrtf(bv4.z + BN_EPS) * bg4.z + bb4.z;
                ov.z = fmaxf(v, 0.f) + r4.z;
                v = sv.w + gb4.w; v = (v - bm4.w) * rsqrtf(bv4.w + BN_EPS) * bg4.w + bb4.w;
                ov.w = fmaxf(v, 0.f) + r4.w;
                *(float4*)(hrow + c) = ov;
                o[i4 * 4 + 0] = ov.x; o[i4 * 4 + 1] = ov.y;
                o[i4 * 4 + 2] = ov.z; o[i4 * 4 + 3] = ov.w;
            }
            {
                __half2 hp[8];
#pragma unroll
                for (int i = 0; i < 8; ++i)
                    hp[i] = __floats2half2_rn(o[2 * i], o[2 * i + 1]);
                uint4 u0, u1;
                u0.x = *(unsigned*)&hp[0]; u0.y = *(unsigned*)&hp[1];
                u0.z = *(unsigned*)&hp[2]; u0.w = *(unsigned*)&hp[3];
                u1.x = *(unsigned*)&hp[4]; u1.y = *(unsigned*)&hp[5];
                u1.z = *(unsigned*)&hp[6]; u1.w = *(unsigned*)&hp[7];
                *(uint4*)(h16 + (size_t)n * HID + c0) = u0;
                *(uint4*)(h16 + (size_t)n * HID + c0 + 8) = u1;
            }
            if (wtsn) {
                float ps0 = 0.f, ps1 = 0.f, ps2 = 0.f, ps3 = 0.f;
                float pd0 = 0.f, pd1 = 0.f, pd2 = 0.f, pd3 = 0.f;
#pragma unroll
                for (int i = 0; i < 16; ++i) {
                    int c = c0 + i;
                    float ov = o[i];
                    ps0 += ov * wtsn[0 * HID + c]; ps1 += ov * wtsn[1 * HID + c];
                    ps2 += ov * wtsn[2 * HID + c]; ps3 += ov * wtsn[3 * HID + c];
                    pd0 += ov * wtdn[0 * HID + c]; pd1 += ov * wtdn[1 * HID + c];
                    pd2 += ov * wtdn[2 * HID + c]; pd3 += ov * wtdn[3 * HID + c];
                }
#pragma unroll
                for (int m = 2; m >= 1; m >>= 1) {
                    ps0 += __shfl_xor(ps0, m, 64); ps1 += __shfl_xor(ps1, m, 64);
                    ps2 += __shfl_xor(ps2, m, 64); ps3 += __shfl_xor(ps3, m, 64);
                    pd0 += __shfl_xor(pd0, m, 64); pd1 += __shfl_xor(pd1, m, 64);
                    pd2 += __shfl_xor(pd2, m, 64); pd3 += __shfl_xor(pd3, m, 64);
                }
                if (q == 0) {
                    *(float4*)(ssrc + (size_t)n * HEADS) = make_float4(ps0, ps1, ps2, ps3);
                    *(float4*)(sdst + (size_t)n * HEADS) = make_float4(pd0, pd1, pd2, pd3);
                }
            }
        }
    }
}

// ---------- global mean pool: node-parallel partial sums ----------
#define NPBK 64
__global__ void k_pool_sum(const float* __restrict__ h, const int* __restrict__ batch,
                           const int* __restrict__ flagp, float* __restrict__ gsum, int N) {
    const int f = *flagp;
    int c = threadIdx.x;  // 0..63
    int n0 = blockIdx.x * NPBK;
    int n1 = min(n0 + NPBK, N);
    if (n0 >= N) return;
    int cur = ld_idx(batch, n0, f);
    float s = 0.f;
    for (int n = n0; n < n1; ++n) {
        int g = ld_idx(batch, n, f);
        if (g != cur) {
            atomicAdd(&gsum[cur * HID + c], s);
            s = 0.f;
            cur = g;
        }
        s += h[(size_t)n * HID + c];
    }
    atomicAdd(&gsum[cur * HID + c], s);
}

__device__ __forceinline__ int lower_bound_i(const int* __restrict__ a, int n, int v, int f) {
    int lo = 0, hi = n;
    while (lo < hi) {
        int mid = (lo + hi) >> 1;
        if (ld_idx(a, mid, f) < v) lo = mid + 1; else hi = mid;
    }
    return lo;
}

// ---------- final MLP head ----------
__global__ void k_mlp(const float* __restrict__ gsum, const int* __restrict__ batch,
                      const int* __restrict__ flagp, int N,
                      const float* __restrict__ W1, const float* __restrict__ b1,
                      const float* __restrict__ W2, const float* __restrict__ b2,
                      float* __restrict__ out, int OUTD) {
    int gg = blockIdx.x, c = threadIdx.x;  // 64 threads
    const int f = *flagp;
    int lo = lower_bound_i(batch, N, gg, f);
    int hi = lower_bound_i(batch, N, gg + 1, f);
    float cnt = (float)(hi - lo);
    __shared__ float gs[HID];
    __shared__ float s1[HID];
    gs[c] = gsum[gg * HID + c] / fmaxf(cnt, 1.f);
    __syncthreads();
    float acc = b1[c];
#pragma unroll
    for (int k = 0; k < HID; ++k) acc += gs[k] * W1[k * HID + c];
    s1[c] = fmaxf(acc, 0.f);
    __syncthreads();
    if (c < OUTD) {
        float o = b2[c];
#pragma unroll
        for (int k = 0; k < HID; ++k) o += s1[k] * W2[k * OUTD + c];
        out[gg * OUTD + c] = o;
    }
}

extern "C" void kernel_launch(void* const* d_in, const int* in_sizes, int n_in,
                              void* d_out, int out_size, void* d_ws, size_t ws_size,
                              hipStream_t stream) {
    const float* x       = (const float*)d_in[0];
    const int*   ei_raw  = (const int*)d_in[1];
    const int*   b_raw   = (const int*)d_in[2];
    const float* in_W    = (const float*)d_in[3];
    const float* in_b    = (const float*)d_in[4];
    const float* gat_W   = (const float*)d_in[5];
    const float* att_src = (const float*)d_in[6];
    const float* att_dst = (const float*)d_in[7];
    const float* gat_b   = (const float*)d_in[8];
    const float* bn_g    = (const float*)d_in[9];
    const float* bn_b    = (const float*)d_in[10];
    const float* bn_m    = (const float*)d_in[11];
    const float* bn_v    = (const float*)d_in[12];
    const float* fc1_W   = (const float*)d_in[13];
    const float* fc1_b   = (const float*)d_in[14];
    const float* fc2_W   = (const float*)d_in[15];
    const float* fc2_b   = (const float*)d_in[16];

    const int N = in_sizes[2];          // n_nodes (<= 65536 for ushort path)
    const int E = in_sizes[1] / 2;      // edges
    const int OUTD = 4;
    const int G = out_size / OUTD;

    // ---- workspace layout (~53.0 MB) ----
    float*  h    = (float*)d_ws;                         // N*64 fp32      12.8 MB
    __half* h16  = (__half*)(h + (size_t)N * HID);       // N*64 fp16       6.4 MB
    __half* agg  = h16 + (size_t)N * HID;                // N*256 fp16     25.6 MB
    float*  ssrc = (float*)(agg + (size_t)N * HC);       // N*4
    float*  sdst = ssrc + (size_t)N * HEADS;             // N*4
    float*  wts  = sdst + (size_t)N * HEADS;             // 3*256
    float*  wtd  = wts + 3 * HC;                         // 3*256
    __half* BT   = (__half*)(wtd + 3 * HC);              // 3*64*256 fp16  96 KB
    float*  gsum = (float*)(BT + 3 * HID * HC);          // G*64
    int*    deg  = (int*)(gsum + (size_t)G * HID);       // N
    unsigned short* src_pad = (unsigned short*)(deg + N);// N*CAP ushort    6.4 MB
    int*    flag = (int*)(src_pad + (size_t)N * CAP);    // 1

    k_init<<<(max(N, G * HID) + 255) / 256, 256, 0, stream>>>(
        ei_raw, flag, deg, gsum, N, G * HID,
        gat_W, att_src, att_dst, wts, wtd, BT);
    k_build<<<(E + 255) / 256, 256, 0, stream>>>(ei_raw, flag, deg, src_pad, E);
    k_input<<<(N + 3) / 4, 256, 0, stream>>>(x, in_W, in_b, wts, wtd, h, h16,
                                             ssrc, sdst, N);

    for (int l = 0; l < 3; ++l) {
        k_gather<<<(N + 3) / 4, 256, 0, stream>>>(
            deg, src_pad, ssrc, sdst, h16, agg, N);
        const float* wtsn = (l < 2) ? (wts + (l + 1) * HC) : nullptr;
        const float* wtdn = (l < 2) ? (wtd + (l + 1) * HC) : nullptr;
        k_postW<<<(N + 63) / 64, 256, 0, stream>>>(
            agg, BT + (size_t)l * HID * HC,
            gat_b + (size_t)l * HID, bn_g + (size_t)l * HID, bn_b + (size_t)l * HID,
            bn_m + (size_t)l * HID, bn_v + (size_t)l * HID,
            wtsn, wtdn, h, h16, ssrc, sdst, N);
    }

    k_pool_sum<<<(N + NPBK - 1) / NPBK, HID, 0, stream>>>(h, b_raw, flag, gsum, N);
    k_mlp<<<G, HID, 0, stream>>>(gsum, b_raw, flag, N, fc1_W, fc1_b, fc2_W, fc2_b,
                                 (float*)d_out, OUTD);
}